// Round 15
// baseline (93.637 us; speedup 1.0000x reference)
//
#include <hip/hip_runtime.h>
#include <math.h>

// Planar normalizing flow, B=524288 rows, D=64, F=32 -- MFMA formulation v4.
//   Phase A (MFMA): S[32f x 64b] = W . X_tile^T   (per 64-row tile)
//   Phase B (VALU): column-update recurrence (critical path = tanh+1 fma)
//   Phase C (MFMA): Z^T-tiles via swapped operands -> f4 epilogue
// r14 (81us) was latency-bound on the per-wave serial chain (VALUBusy 22%,
// MfmaUtil 3.5%, occ 38%: all pipes idle). v4 cuts the two biggest chain
// segments, register-neutrally:
//  - Phase B: per-step fresh dot (8 serial FMAs + s_load exposure in-chain)
//    -> push-forward updates sa[g] += Gc[f][g]*h[f]; chain = tanh->fma.
//    Gc rows zero for g<=f, so h[f] is stashed IN sa (no hq array).
//  - Phase C: MFMA(Uf,Hf) gives lanes consecutive-d quads -> 16 f4 stores
//    + 16 f4 x-reloads instead of 128 scalar VMEM ops.

#define NF_D 64
#define NF_F 32

typedef float f4 __attribute__((ext_vector_type(4)));
typedef float f32x4v __attribute__((ext_vector_type(4)));
typedef unsigned int u32;
typedef u32 u32x4 __attribute__((ext_vector_type(4)));
typedef short bf16x8 __attribute__((ext_vector_type(8)));

// wsbuf layout in 4-byte units:
#define WS_WF   0       // u32[8][64][4]  W A-frags, lin=(Mt*2+Kt)*2+p
#define WS_UF   2048    // u32[4][64][4]  Uhat frags (lane&15=d, k=f)
#define WS_GT   3072    // float[32][32]  Gc[f][g]=w_g.uhat_f (g>f else 0)
#define WS_WUH  4096    // float[32]      w_f.uhat_f
#define WS_TOT  4128

__device__ __forceinline__ u32 fbits(float x){ union{float f;u32 u;} c; c.f=x; return c.u; }
__device__ __forceinline__ float asf(u32 u){ union{u32 u;float f;} c; c.u=u; return c.f; }
__device__ __forceinline__ u32 bfrnd(float x){ u32 b=fbits(x); return (b + 0x7FFFu + ((b>>16)&1u)) >> 16; }
__device__ __forceinline__ bf16x8 asbf(u32x4 v){ union{u32x4 u; bf16x8 b;} c; c.u=v; return c.b; }

// --- precompute: uhat, wuh, Gc (transposed), W/U fragment buffers --------
__global__ void nf_precompute(const float* __restrict__ us,
                              const float* __restrict__ ws,
                              u32* __restrict__ wsb) {
  __shared__ float s_u[NF_F][NF_D];
  float* wsf = (float*)wsb;
  int t = threadIdx.x;
  if (t < NF_F) {
    const float* u = us + t * NF_D;
    const float* w = ws + t * NF_D;
    float wu = 0.f, n2 = 0.f;
    for (int d = 0; d < NF_D; ++d) {
      wu = fmaf(u[d], w[d], wu);
      n2 = fmaf(w[d], w[d], n2);
    }
    float sp = fmaxf(wu, 0.f) + log1pf(expf(-fabsf(wu)));  // softplus
    float coef = (sp - 1.f - wu) / sqrtf(n2);
    for (int d = 0; d < NF_D; ++d)
      s_u[t][d] = fmaf(coef, w[d], u[d]);                  // uhat
    wsf[WS_WUH + t] = fmaf(coef, n2, wu);                  // w_t.uhat_t
  }
  __syncthreads();
  // W A-frags: lane l holds W[fm=16Mt+(l&15)][k=32Kt+8*(l>>4)+j], j=0..7
  // p=0: bf16-trunc(hi); p=1: bf16-trunc(w - hi)
  for (int idx = t; idx < 8 * 64; idx += 256) {
    int lin = idx >> 6, l = idx & 63;
    int Mt = lin >> 2, Kt = (lin >> 1) & 1, p = lin & 1;
    int fm = 16 * Mt + (l & 15);
    int kb = 32 * Kt + 8 * (l >> 4);
    for (int i = 0; i < 4; ++i) {
      u32 pr[2];
      for (int e = 0; e < 2; ++e) {
        float w = ws[fm * NF_D + kb + 2 * i + e];
        u32 hb = fbits(w) & 0xFFFF0000u;
        pr[e] = (p == 0) ? (hb >> 16) : (fbits(w - asf(hb)) >> 16);
      }
      wsb[WS_WF + (lin * 64 + l) * 4 + i] = pr[0] | (pr[1] << 16);
    }
  }
  // U frags: lane l holds Uhat[f=8*(l>>4)+j][d=16Nt+(l&15)], rounded bf16
  for (int idx = t; idx < 4 * 64; idx += 256) {
    int l = idx & 63;
    int d = 16 * (idx >> 6) + (l & 15);
    int fb = 8 * (l >> 4);
    for (int i = 0; i < 4; ++i) {
      u32 r0 = bfrnd(s_u[fb + 2 * i][d]);
      u32 r1 = bfrnd(s_u[fb + 2 * i + 1][d]);
      wsb[WS_UF + idx * 4 + i] = r0 | (r1 << 16);
    }
  }
  // Gc[f][g] = w_g . uhat_f for g>f, else 0 (column form of G)
  for (int i = t; i < NF_F * NF_F; i += 256) {
    int f = i >> 5, g = i & 31;
    float s = 0.f;
    if (g > f) {
      const float* w = ws + g * NF_D;
      for (int d = 0; d < NF_D; ++d) s = fmaf(s_u[f][d], w[d], s);
    }
    wsf[WS_GT + i] = s;
  }
}

// tanh(x) = 1 - 2/(e^{2x}+1); hardware exp2/rcp; saturates to +-1.
__device__ __forceinline__ float fast_tanh(float x) {
  float e = __builtin_amdgcn_exp2f(x * 2.885390081777927f); // 2*log2(e)
  return 1.f - 2.f * __builtin_amdgcn_rcpf(e + 1.f);
}

#define MFMA __builtin_amdgcn_mfma_f32_16x16x32_bf16

// --- main: one 64-row tile per wave, no block barriers -------------------
__global__ __launch_bounds__(256) void nf_main(
    const float* __restrict__ x,
    const float* __restrict__ bs,
    const u32* __restrict__ wsb,
    float* __restrict__ out_z,
    float* __restrict__ out_ld,
    int B) {
  // Per-wave scratch: S[b][f] stride 33 (phase A->B); words [0,1024)
  // reused for packed-h (phase B->C). Same-wave program-order reuse only.
  __shared__ float S[4][64 * 33];
  const float* wsf = (const float*)wsb;

  int wave = threadIdx.x >> 6;
  int l = threadIdx.x & 63;
  int ntiles = B / 64;
  int tile = blockIdx.x * 4 + wave;
  if (tile >= ntiles) tile = ntiles - 1;   // safety clamp (grid is exact)
  float* Sw = S[wave];

  // persistent param fragments (once per wave)
  bf16x8 Wf[2][2][2], Uf[4];
  #pragma unroll
  for (int q = 0; q < 8; ++q)
    Wf[q >> 2][(q >> 1) & 1][q & 1] =
        asbf(*(const u32x4*)(wsb + WS_WF + (q * 64 + l) * 4));
  #pragma unroll
  for (int Nt = 0; Nt < 4; ++Nt)
    Uf[Nt] = asbf(*(const u32x4*)(wsb + WS_UF + (Nt * 64 + l) * 4));

  const float* xt = x + (size_t)tile * 64 * NF_D;

  // ---- Phase A: S = W . X^T (split bf16, 3 passes) ----------------------
  #pragma unroll
  for (int Nt = 0; Nt < 4; ++Nt) {
    bf16x8 Xh[2], Xl[2];
    #pragma unroll
    for (int Kt = 0; Kt < 2; ++Kt) {
      const f4* xp = (const f4*)(xt + ((l & 15) + 16 * Nt) * NF_D +
                                 32 * Kt + 8 * (l >> 4));
      f4 xa = xp[0], xb = xp[1];
      float xs[8] = {xa.x, xa.y, xa.z, xa.w, xb.x, xb.y, xb.z, xb.w};
      u32x4 hw, lw;
      #pragma unroll
      for (int i = 0; i < 4; ++i) {
        u32 b0 = fbits(xs[2 * i]), b1 = fbits(xs[2 * i + 1]);
        u32 h0 = b0 & 0xFFFF0000u, h1 = b1 & 0xFFFF0000u;
        hw[i] = (h0 >> 16) | h1;
        lw[i] = (fbits(xs[2 * i] - asf(h0)) >> 16) |
                (fbits(xs[2 * i + 1] - asf(h1)) & 0xFFFF0000u);
      }
      Xh[Kt] = asbf(hw);
      Xl[Kt] = asbf(lw);
    }
    #pragma unroll
    for (int Mt = 0; Mt < 2; ++Mt) {
      f32x4v a = {0.f, 0.f, 0.f, 0.f};
      #pragma unroll
      for (int Kt = 0; Kt < 2; ++Kt) {
        a = MFMA(Wf[Mt][Kt][0], Xh[Kt], a, 0, 0, 0);
        a = MFMA(Wf[Mt][Kt][0], Xl[Kt], a, 0, 0, 0);
        a = MFMA(Wf[Mt][Kt][1], Xh[Kt], a, 0, 0, 0);
      }
      // scatter S: C/D layout col=lane&15 (b in Ntile), row=4*(l>>4)+r
      #pragma unroll
      for (int r = 0; r < 4; ++r)
        Sw[((l & 15) + 16 * Nt) * 33 + 16 * Mt + 4 * (l >> 4) + r] = a[r];
    }
  }

  // ---- Phase B: column-update recurrence (lane = row b) -----------------
  // sa[g] starts as S[b][g] + bs[g]; after h[f] is computed it is pushed
  // into all later accumulators (Gc[f][g]=0 for g<=f), and h[f] is stashed
  // in sa element f (later Gc rows leave elements <= f untouched).
  const float* gc = wsf + WS_GT;
  const float* wuhp = wsf + WS_WUH;
  const f4* bs4 = (const f4*)bs;
  f4 sa[8];
  #pragma unroll
  for (int q = 0; q < 8; ++q) {
    f4 sv;
    #pragma unroll
    for (int e = 0; e < 4; ++e) sv[e] = Sw[l * 33 + 4 * q + e];
    sa[q] = sv + bs4[q];
  }
  float ldp = 1.f;
  #pragma unroll
  for (int f = 0; f < NF_F; ++f) {
    float hf = fast_tanh(sa[f >> 2][f & 3]);
    ldp *= fmaf(fmaf(-hf, hf, 1.f), wuhp[f], 1.f);
    const f4* gr = (const f4*)(gc + f * 32);
    #pragma unroll
    for (int q = f >> 2; q < 8; ++q)     // rows are zero-padded for g<=f
      sa[q] += gr[q] * hf;
    sa[f >> 2][f & 3] = hf;              // stash h[f] in place
  }
  // pack h -> bf16 pairs into S words [0,1024): Hw[i][b], b = lane.
  #pragma unroll
  for (int i = 0; i < 16; ++i) {
    u32 pk = (fbits(sa[i >> 1][(i & 1) * 2]) >> 16) |
             (fbits(sa[i >> 1][(i & 1) * 2 + 1]) & 0xFFFF0000u);
    Sw[i * 64 + l] = asf(pk);
  }

  // ---- Phase C: Z^T-tiles = Uhat^T . H (swapped operands) ---------------
  bf16x8 Hf[4];
  #pragma unroll
  for (int Nt = 0; Nt < 4; ++Nt) {       // n = b = (l&15)+16Nt, k = f
    u32x4 hw;
    #pragma unroll
    for (int i = 0; i < 4; ++i)
      hw[i] = fbits(Sw[(4 * (l >> 4) + i) * 64 + (l & 15) + 16 * Nt]);
    Hf[Nt] = asbf(hw);
  }

  float* zt = out_z + (size_t)tile * 64 * NF_D;
  #pragma unroll
  for (int Ntb = 0; Ntb < 4; ++Ntb) {    // b tile (cols of D)
    #pragma unroll
    for (int Mtd = 0; Mtd < 4; ++Mtd) {  // d tile (row-quads of D)
      f32x4v zz = {0.f, 0.f, 0.f, 0.f};
      zz = MFMA(Uf[Mtd], Hf[Ntb], zz, 0, 0, 0);
      int b = (l & 15) + 16 * Ntb;
      int d0 = 16 * Mtd + 4 * (l >> 4);
      f4 xr = *(const f4*)(xt + b * NF_D + d0);   // L1/L2-hot re-read
      f4 zv = {zz[0] + xr.x, zz[1] + xr.y, zz[2] + xr.z, zz[3] + xr.w};
      *(f4*)(zt + b * NF_D + d0) = zv;            // one f4 store per MFMA
    }
  }
  out_ld[(size_t)tile * 64 + l] =
      __builtin_amdgcn_logf(fabsf(ldp)) * 0.6931471805599453f;
}

extern "C" void kernel_launch(void* const* d_in, const int* in_sizes, int n_in,
                              void* d_out, int out_size, void* d_ws, size_t ws_size,
                              hipStream_t stream) {
  const float* x    = (const float*)d_in[0];
  const float* us   = (const float*)d_in[1];
  const float* ws_p = (const float*)d_in[2];
  const float* bs   = (const float*)d_in[3];
  const int B = in_sizes[0] / NF_D;

  u32* wsbuf = (u32*)d_ws;       // WS_TOT u32 ~ 16.5 KB
  float* out = (float*)d_out;    // z [B*64] then sum_log_det [B]

  nf_precompute<<<1, 256, 0, stream>>>(us, ws_p, wsbuf);
  const int ntiles = B / 64;
  const int grid = (ntiles + 3) / 4;
  nf_main<<<grid, 256, 0, stream>>>(x, bs, wsbuf, out,
                                    out + (size_t)B * NF_D, B);
}

// Round 16
// 85.868 us; speedup vs baseline: 1.0905x; 1.0905x over previous
//
#include <hip/hip_runtime.h>
#include <math.h>

// Planar normalizing flow, B=524288 rows, D=64, F=32 -- MFMA formulation v5.
//   Phase A (MFMA): S[32f x 64b] = W . X_tile^T   (per 64-row tile)
//   Phase B (VALU): per-lane recurrence, r14 form (fresh f4 dot per step;
//                   S reads are recurrence-independent -> compiler hoists)
//   Phase C (MFMA): Z^T-tiles via swapped operands -> f4 epilogue (r15,
//                   correctness-verified)
// vs r14 (81us, occ 38%, all pipes <40% = latency-bound):
//  - S uses XOR-swizzled stride 32 (S[b*32 + (f ^ (b&31))]): bank-bijective
//    for both the phase-A write pattern (varying b) and phase-B read
//    pattern (varying f), same conflicts as stride-33, but 8448->8192 B
//    per wave -> 32KB/block -> 5 blocks/CU (was 4): +25% TLP.
//  - phase C swap: 128 scalar VMEM -> 16 f4 loads + 16 f4 stores.
//  - phase B unchanged from r14 (r15's column-update raised VGPR 56->72
//    and occupancy fell; reverted).

#define NF_D 64
#define NF_F 32

typedef float f4 __attribute__((ext_vector_type(4)));
typedef float f32x4v __attribute__((ext_vector_type(4)));
typedef unsigned int u32;
typedef u32 u32x4 __attribute__((ext_vector_type(4)));
typedef short bf16x8 __attribute__((ext_vector_type(8)));

// wsbuf layout in 4-byte units:
#define WS_WF   0       // u32[8][64][4]  W A-frags, lin=(Mt*2+Kt)*2+p
#define WS_UF   2048    // u32[4][64][4]  Uhat frags (lane&15=d, k=f)
#define WS_GT   3072    // float[32][32]  G[f][g]=u_hat_g.w_f (g<f else 0)
#define WS_WUH  4096    // float[32]      w_f.uhat_f
#define WS_TOT  4128

__device__ __forceinline__ u32 fbits(float x){ union{float f;u32 u;} c; c.f=x; return c.u; }
__device__ __forceinline__ float asf(u32 u){ union{u32 u;float f;} c; c.u=u; return c.f; }
__device__ __forceinline__ u32 bfrnd(float x){ u32 b=fbits(x); return (b + 0x7FFFu + ((b>>16)&1u)) >> 16; }
__device__ __forceinline__ bf16x8 asbf(u32x4 v){ union{u32x4 u; bf16x8 b;} c; c.u=v; return c.b; }

// --- precompute: uhat, wuh, G, W/U fragment buffers ----------------------
__global__ void nf_precompute(const float* __restrict__ us,
                              const float* __restrict__ ws,
                              u32* __restrict__ wsb) {
  __shared__ float s_u[NF_F][NF_D];
  float* wsf = (float*)wsb;
  int t = threadIdx.x;
  if (t < NF_F) {
    const float* u = us + t * NF_D;
    const float* w = ws + t * NF_D;
    float wu = 0.f, n2 = 0.f;
    for (int d = 0; d < NF_D; ++d) {
      wu = fmaf(u[d], w[d], wu);
      n2 = fmaf(w[d], w[d], n2);
    }
    float sp = fmaxf(wu, 0.f) + log1pf(expf(-fabsf(wu)));  // softplus
    float coef = (sp - 1.f - wu) / sqrtf(n2);
    for (int d = 0; d < NF_D; ++d)
      s_u[t][d] = fmaf(coef, w[d], u[d]);                  // uhat
    wsf[WS_WUH + t] = fmaf(coef, n2, wu);                  // w_t.uhat_t
  }
  __syncthreads();
  // W A-frags: lane l holds W[fm=16Mt+(l&15)][k=32Kt+8*(l>>4)+j], j=0..7
  // p=0: bf16-trunc(hi); p=1: bf16-trunc(w - hi)
  for (int idx = t; idx < 8 * 64; idx += 256) {
    int lin = idx >> 6, l = idx & 63;
    int Mt = lin >> 2, Kt = (lin >> 1) & 1, p = lin & 1;
    int fm = 16 * Mt + (l & 15);
    int kb = 32 * Kt + 8 * (l >> 4);
    for (int i = 0; i < 4; ++i) {
      u32 pr[2];
      for (int e = 0; e < 2; ++e) {
        float w = ws[fm * NF_D + kb + 2 * i + e];
        u32 hb = fbits(w) & 0xFFFF0000u;
        pr[e] = (p == 0) ? (hb >> 16) : (fbits(w - asf(hb)) >> 16);
      }
      wsb[WS_WF + (lin * 64 + l) * 4 + i] = pr[0] | (pr[1] << 16);
    }
  }
  // U frags: lane l holds Uhat[f=8*(l>>4)+j][d=16Nt+(l&15)], rounded bf16
  for (int idx = t; idx < 4 * 64; idx += 256) {
    int l = idx & 63;
    int d = 16 * (idx >> 6) + (l & 15);
    int fb = 8 * (l >> 4);
    for (int i = 0; i < 4; ++i) {
      u32 r0 = bfrnd(s_u[fb + 2 * i][d]);
      u32 r1 = bfrnd(s_u[fb + 2 * i + 1][d]);
      wsb[WS_UF + idx * 4 + i] = r0 | (r1 << 16);
    }
  }
  // G[f][g] = u_hat_g . w_f for g<f, else 0
  for (int i = t; i < NF_F * NF_F; i += 256) {
    int f = i >> 5, g = i & 31;
    float s = 0.f;
    if (g < f) {
      const float* w = ws + f * NF_D;
      for (int d = 0; d < NF_D; ++d) s = fmaf(s_u[g][d], w[d], s);
    }
    wsf[WS_GT + i] = s;
  }
}

// tanh(x) = 1 - 2/(e^{2x}+1); hardware exp2/rcp; saturates to +-1.
__device__ __forceinline__ float fast_tanh(float x) {
  float e = __builtin_amdgcn_exp2f(x * 2.885390081777927f); // 2*log2(e)
  return 1.f - 2.f * __builtin_amdgcn_rcpf(e + 1.f);
}

#define MFMA __builtin_amdgcn_mfma_f32_16x16x32_bf16

// --- main: one 64-row tile per wave, no block barriers -------------------
__global__ __launch_bounds__(256) void nf_main(
    const float* __restrict__ x,
    const float* __restrict__ bs,
    const u32* __restrict__ wsb,
    float* __restrict__ out_z,
    float* __restrict__ out_ld,
    int B) {
  // Per-wave scratch, 2048 floats: S[b][f] at S[b*32 + (f ^ (b&31))]
  // (XOR keeps every access pattern bank-bijective); words [0,1024)
  // reused for packed-h (phase B->C). Same-wave program-order reuse only.
  __shared__ float S[4][2048];
  const float* wsf = (const float*)wsb;

  int wave = threadIdx.x >> 6;
  int l = threadIdx.x & 63;
  int ntiles = B / 64;
  int tile = blockIdx.x * 4 + wave;
  if (tile >= ntiles) tile = ntiles - 1;   // safety clamp (grid is exact)
  float* Sw = S[wave];

  // persistent param fragments (once per wave)
  bf16x8 Wf[2][2][2], Uf[4];
  #pragma unroll
  for (int q = 0; q < 8; ++q)
    Wf[q >> 2][(q >> 1) & 1][q & 1] =
        asbf(*(const u32x4*)(wsb + WS_WF + (q * 64 + l) * 4));
  #pragma unroll
  for (int Nt = 0; Nt < 4; ++Nt)
    Uf[Nt] = asbf(*(const u32x4*)(wsb + WS_UF + (Nt * 64 + l) * 4));

  const float* xt = x + (size_t)tile * 64 * NF_D;

  // ---- Phase A: S = W . X^T (split bf16, 3 passes) ----------------------
  #pragma unroll
  for (int Nt = 0; Nt < 4; ++Nt) {
    bf16x8 Xh[2], Xl[2];
    #pragma unroll
    for (int Kt = 0; Kt < 2; ++Kt) {
      const f4* xp = (const f4*)(xt + ((l & 15) + 16 * Nt) * NF_D +
                                 32 * Kt + 8 * (l >> 4));
      f4 xa = xp[0], xb = xp[1];
      float xs[8] = {xa.x, xa.y, xa.z, xa.w, xb.x, xb.y, xb.z, xb.w};
      u32x4 hw, lw;
      #pragma unroll
      for (int i = 0; i < 4; ++i) {
        u32 b0 = fbits(xs[2 * i]), b1 = fbits(xs[2 * i + 1]);
        u32 h0 = b0 & 0xFFFF0000u, h1 = b1 & 0xFFFF0000u;
        hw[i] = (h0 >> 16) | h1;
        lw[i] = (fbits(xs[2 * i] - asf(h0)) >> 16) |
                (fbits(xs[2 * i + 1] - asf(h1)) & 0xFFFF0000u);
      }
      Xh[Kt] = asbf(hw);
      Xl[Kt] = asbf(lw);
    }
    #pragma unroll
    for (int Mt = 0; Mt < 2; ++Mt) {
      f32x4v a = {0.f, 0.f, 0.f, 0.f};
      #pragma unroll
      for (int Kt = 0; Kt < 2; ++Kt) {
        a = MFMA(Wf[Mt][Kt][0], Xh[Kt], a, 0, 0, 0);
        a = MFMA(Wf[Mt][Kt][0], Xl[Kt], a, 0, 0, 0);
        a = MFMA(Wf[Mt][Kt][1], Xh[Kt], a, 0, 0, 0);
      }
      // scatter S: C/D layout col=lane&15 (b in Ntile), row=4*(l>>4)+r
      int b = (l & 15) + 16 * Nt;
      int fc = 16 * Mt + 4 * (l >> 4);
      #pragma unroll
      for (int r = 0; r < 4; ++r)
        Sw[b * 32 + ((fc + r) ^ (b & 31))] = a[r];
    }
  }

  // ---- Phase B: per-lane row recurrence (lane = row b), r14 form --------
  const float* gt = wsf + WS_GT;
  const float* wuhp = wsf + WS_WUH;
  f4 hq[8];
  #pragma unroll
  for (int q = 0; q < 8; ++q) hq[q] = (f4)(0.f);   // zero: G pads are 0
  float ldp = 1.f;
  #pragma unroll
  for (int f = 0; f < NF_F; ++f) {
    const f4* g4 = (const f4*)(gt + f * 32);
    f4 a = (f4)(0.f);
    #pragma unroll
    for (int q = 0; q < (f + 3) / 4; ++q)
      a += g4[q] * hq[q];                  // chain f/4; pads hit G zeros
    float s = Sw[l * 32 + (f ^ (l & 31))] + bs[f] +
              ((a.x + a.y) + (a.z + a.w));
    float hf = fast_tanh(s);
    ldp *= fmaf(fmaf(-hf, hf, 1.f), wuhp[f], 1.f);
    hq[f >> 2][f & 3] = hf;
  }
  // pack h -> bf16 pairs into S words [0,1024): Hw[i][b], b = lane.
  #pragma unroll
  for (int i = 0; i < 16; ++i) {
    u32 pk = (fbits(hq[i >> 1][(i & 1) * 2]) >> 16) |
             (fbits(hq[i >> 1][(i & 1) * 2 + 1]) & 0xFFFF0000u);
    Sw[i * 64 + l] = asf(pk);
  }

  // ---- Phase C: Z^T-tiles = Uhat^T . H (swapped operands, r15) ----------
  bf16x8 Hf[4];
  #pragma unroll
  for (int Nt = 0; Nt < 4; ++Nt) {       // n = b = (l&15)+16Nt, k = f
    u32x4 hw;
    #pragma unroll
    for (int i = 0; i < 4; ++i)
      hw[i] = fbits(Sw[(4 * (l >> 4) + i) * 64 + (l & 15) + 16 * Nt]);
    Hf[Nt] = asbf(hw);
  }

  float* zt = out_z + (size_t)tile * 64 * NF_D;
  #pragma unroll
  for (int Ntb = 0; Ntb < 4; ++Ntb) {    // b tile
    #pragma unroll
    for (int Mtd = 0; Mtd < 4; ++Mtd) {  // d tile (row-quads of D)
      f32x4v zz = {0.f, 0.f, 0.f, 0.f};
      zz = MFMA(Uf[Mtd], Hf[Ntb], zz, 0, 0, 0);
      int b = (l & 15) + 16 * Ntb;
      int d0 = 16 * Mtd + 4 * (l >> 4);
      f4 xr = *(const f4*)(xt + b * NF_D + d0);   // L3-hot re-read
      f4 zv = {zz[0] + xr.x, zz[1] + xr.y, zz[2] + xr.z, zz[3] + xr.w};
      *(f4*)(zt + b * NF_D + d0) = zv;            // one f4 store per MFMA
    }
  }
  out_ld[(size_t)tile * 64 + l] =
      __builtin_amdgcn_logf(fabsf(ldp)) * 0.6931471805599453f;
}

extern "C" void kernel_launch(void* const* d_in, const int* in_sizes, int n_in,
                              void* d_out, int out_size, void* d_ws, size_t ws_size,
                              hipStream_t stream) {
  const float* x    = (const float*)d_in[0];
  const float* us   = (const float*)d_in[1];
  const float* ws_p = (const float*)d_in[2];
  const float* bs   = (const float*)d_in[3];
  const int B = in_sizes[0] / NF_D;

  u32* wsbuf = (u32*)d_ws;       // WS_TOT u32 ~ 16.5 KB
  float* out = (float*)d_out;    // z [B*64] then sum_log_det [B]

  nf_precompute<<<1, 256, 0, stream>>>(us, ws_p, wsbuf);
  const int ntiles = B / 64;
  const int grid = (ntiles + 3) / 4;
  nf_main<<<grid, 256, 0, stream>>>(x, bs, wsbuf, out,
                                    out + (size_t)B * NF_D, B);
}